// Round 4
// baseline (509.207 us; speedup 1.0000x reference)
//
#include <hip/hip_runtime.h>
#include <math.h>

#define B_ 8
#define T1_ 32
#define T2_ 32
#define T3_ 16
#define D_ 512
#define L_ 20
#define DL_ 128
#define M_ (B_*T1_*T2_*T3_)   // 131072

// workspace layout (float offsets)
#define WS_FW   0                      // B*L*DL
#define WS_KQ   20480                  // B*L*DL
#define WS_FS   40960                  // B*DL
#define WS_SB   41984                  // B*L
#define WS_WDB  42144                  // Wc_down bf16: 65536 ushort
#define WS_WUB  74912                  // Wc_up   bf16: 65536 ushort

typedef __attribute__((ext_vector_type(8))) short short8_t;
typedef __attribute__((ext_vector_type(4))) float f32x4;

__device__ __forceinline__ unsigned short f2b(float f) {
  unsigned int u = __float_as_uint(f);
  return (unsigned short)((u + 0x7fffu + ((u >> 16) & 1u)) >> 16);
}
__device__ __forceinline__ float b2f(short s) {
  return __uint_as_float(((unsigned)(unsigned short)s) << 16);
}
__device__ __forceinline__ int4 pack8(float4 a, float4 b) {
  int4 p;
  p.x = (int)f2b(a.x) | ((int)f2b(a.y) << 16);
  p.y = (int)f2b(a.z) | ((int)f2b(a.w) << 16);
  p.z = (int)f2b(b.x) | ((int)f2b(b.y) << 16);
  p.w = (int)f2b(b.z) | ((int)f2b(b.w) << 16);
  return p;
}

// ---------------------------------------------------------------------------
// K0: convert Wc_down [128][512] and Wc_up [512][128] fp32 -> bf16 in ws
// ---------------------------------------------------------------------------
__global__ __launch_bounds__(256) void k0_convert(
    const float* __restrict__ Wd, const float* __restrict__ Wu,
    unsigned short* __restrict__ wdb, unsigned short* __restrict__ wub) {
  int g = blockIdx.x * 256 + threadIdx.x;      // 0..32767
  if (g < 16384) {
    float4 v = ((const float4*)Wd)[g];
    ushort4 h; h.x = f2b(v.x); h.y = f2b(v.y); h.z = f2b(v.z); h.w = f2b(v.w);
    ((ushort4*)wdb)[g] = h;
  } else {
    int q = g - 16384;
    float4 v = ((const float4*)Wu)[q];
    ushort4 h; h.x = f2b(v.x); h.y = f2b(v.y); h.z = f2b(v.z); h.w = f2b(v.w);
    ((ushort4*)wub)[q] = h;
  }
}

// ---------------------------------------------------------------------------
// K1: tiny projections. grid = B*L blocks, 128 threads.
// ---------------------------------------------------------------------------
__global__ __launch_bounds__(128) void k1_small(
    const float* __restrict__ f_w, const float* __restrict__ f_s,
    const float* __restrict__ Ww, const float* __restrict__ bw,
    const float* __restrict__ Ws, const float* __restrict__ bs,
    const float* __restrict__ Wq, const float* __restrict__ bq,
    const float* __restrict__ Wk, const float* __restrict__ bk,
    float* __restrict__ ws) {
  const int bl = blockIdx.x;
  const int b = bl / L_, l = bl % L_;
  const int d = threadIdx.x;
  __shared__ float s_fw[DL_];
  __shared__ float s_k[DL_];
  {
    const float* x = f_w + (size_t)(b*L_+l)*D_;
    const float* w = Ww + (size_t)d*D_;
    float acc = 0.f;
    for (int i = 0; i < D_; i += 4)
      acc += x[i]*w[i] + x[i+1]*w[i+1] + x[i+2]*w[i+2] + x[i+3]*w[i+3];
    acc += bw[d];
    s_fw[d] = acc;
    ws[WS_FW + (b*L_+l)*DL_ + d] = acc;
  }
  if (l == 0) {
    const float* x = f_s + (size_t)b*D_;
    const float* w = Ws + (size_t)d*D_;
    float acc = 0.f;
    for (int i = 0; i < D_; i += 4)
      acc += x[i]*w[i] + x[i+1]*w[i+1] + x[i+2]*w[i+2] + x[i+3]*w[i+3];
    ws[WS_FS + b*DL_ + d] = acc + bs[d];
  }
  __syncthreads();
  {
    const float* w = Wk + (size_t)d*DL_;
    float acc = 0.f;
    for (int i = 0; i < DL_; ++i) acc += s_fw[i]*w[i];
    s_k[d] = acc + bk[d];
  }
  __syncthreads();
  {
    float acc = 0.f;
    for (int c = 0; c < DL_; ++c) acc += s_k[c] * Wq[c*DL_ + d];
    ws[WS_KQ + (b*L_+l)*DL_ + d] = acc;
  }
  if (d == 0) {
    float acc = 0.f;
    for (int c = 0; c < DL_; ++c) acc += bq[c]*s_k[c];
    ws[WS_SB + b*L_ + l] = acc;
  }
}

// ---------------------------------------------------------------------------
// K2: fused per 32-row tile. A=weights, B=activations (vectorized epilogue).
// Staged+reg-prefetched GEMM chunks; 36.9 KB LDS -> 4 blocks/CU.
// ---------------------------------------------------------------------------
// LDS byte offsets
#define SFCH_B 0        // f_c_hat bf16 [32][256B], XOR-swizzled
#define FCQ_B  8192     // f_cq / f_cc_hat bf16 [32][256B], swizzled
#define WD_B   16384    // down: Wd chunk [128][128B]
#define FC_B   32768    // down: f_c chunk [32][128B]
#define KQ_B   16384    // mid: kq bf16 [20][272B]
#define FW_B   21824    // mid: fw bf16 [20][272B]
#define FS_B   27264    // mid: f_s_hat f32 [128]
#define SB_B   27776    // mid: sb f32 [20]
#define ATTN_B 27904    // mid: attn f32 [32][21]
#define AC_B   30592    // mid: A_c f32 [32][17]
#define WU_B   16384    // up: Wu chunk [64][256B]
#define SMEM_B 36864

__global__ __launch_bounds__(256, 4) void k2_fused(
    const float* __restrict__ f_c, const unsigned short* __restrict__ wdb,
    const unsigned short* __restrict__ wub,
    const float* __restrict__ bc_down, const float* __restrict__ bc_up,
    const float* __restrict__ f_m, const float* __restrict__ f_s,
    const float* __restrict__ ws, float* __restrict__ out) {
  __shared__ __align__(16) char smb[SMEM_B];
  float* sAttn = (float*)(smb + ATTN_B);
  float* sAc   = (float*)(smb + AC_B);
  float* sFs   = (float*)(smb + FS_B);
  float* sSb   = (float*)(smb + SB_B);

  const int t = threadIdx.x;
  const int row0 = blockIdx.x * 32;
  const int b = row0 >> 14;
  const int lane = t & 63, w = t >> 6;
  const int l15 = lane & 15, l4 = lane >> 4;
  const int wr = (w & 1) * 16;        // activation-row group
  const int wc = w >> 1;              // d-col group
  const float inv_sqrt_dl = 0.08838834764831843f;
  const f32x4 z4 = {0.f, 0.f, 0.f, 0.f};

  // ---------------- down GEMM: staged chunks + reg prefetch ----------------
  int4 wreg[4]; int4 fcreg;
  const int sd_r = t >> 3, sd_k8 = (t & 7) * 8;   // f_c staging coords
  auto load_down = [&](int kc) {
    #pragma unroll
    for (int i = 0; i < 4; ++i) {
      int idx = t + i*256;
      wreg[i] = *(const int4*)(wdb + (size_t)(idx >> 3)*D_ + kc + (idx & 7)*8);
    }
    const float* src = f_c + (size_t)(row0 + sd_r)*D_ + kc + sd_k8;
    float4 v0 = *(const float4*)src;
    float4 v1 = *(const float4*)(src + 4);
    fcreg = pack8(v0, v1);
  };

  f32x4 dacc[4];
  #pragma unroll
  for (int cf = 0; cf < 4; ++cf) dacc[cf] = z4;

  load_down(0);
  for (int kc = 0; kc < D_; kc += 64) {
    __syncthreads();
    #pragma unroll
    for (int i = 0; i < 4; ++i) {
      int idx = t + i*256;
      int d = idx >> 3, kb = (idx & 7) * 16;
      *(int4*)(smb + WD_B + d*128 + (kb ^ ((d & 7) << 4))) = wreg[i];
    }
    *(int4*)(smb + FC_B + sd_r*128 + ((sd_k8*2) ^ ((sd_r & 7) << 4))) = fcreg;
    __syncthreads();
    if (kc + 64 < D_) load_down(kc + 64);
    #pragma unroll
    for (int ks = 0; ks < 2; ++ks) {
      const int rr = wr + l15;
      short8_t bfrag = *(const short8_t*)(smb + FC_B + rr*128 +
                        ((ks*64 + l4*16) ^ ((rr & 7) << 4)));
      #pragma unroll
      for (int cf = 0; cf < 4; ++cf) {
        const int d = wc*64 + cf*16 + l15;
        short8_t afrag = *(const short8_t*)(smb + WD_B + d*128 +
                          ((ks*64 + l4*16) ^ ((d & 7) << 4)));
        dacc[cf] = __builtin_amdgcn_mfma_f32_16x16x32_bf16(afrag, bfrag, dacc[cf], 0, 0, 0);
      }
    }
  }
  // writeout f_c_hat: lane holds row rr = wr+l15, d0..d0+3 consecutive
  {
    const int rr = wr + l15;
    const int rs = (rr & 7) << 4;
    #pragma unroll
    for (int cf = 0; cf < 4; ++cf) {
      const int d0 = wc*64 + cf*16 + l4*4;
      float4 bias = *(const float4*)(bc_down + d0);
      ushort4 pk;
      pk.x = f2b(dacc[cf][0] + bias.x); pk.y = f2b(dacc[cf][1] + bias.y);
      pk.z = f2b(dacc[cf][2] + bias.z); pk.w = f2b(dacc[cf][3] + bias.w);
      *(ushort4*)(smb + SFCH_B + rr*256 + ((d0*2) ^ rs)) = pk;
    }
  }
  __syncthreads();
  // stage per-batch smalls into C region (down staging now dead)
  for (int p = t; p < L_*16; p += 256) {
    const int l = p >> 4, c8 = (p & 15) * 8;
    float4 a0 = *(const float4*)(ws + WS_KQ + (b*L_+l)*DL_ + c8);
    float4 a1 = *(const float4*)(ws + WS_KQ + (b*L_+l)*DL_ + c8 + 4);
    *(int4*)(smb + KQ_B + l*272 + c8*2) = pack8(a0, a1);
    float4 b0 = *(const float4*)(ws + WS_FW + (b*L_+l)*DL_ + c8);
    float4 b1 = *(const float4*)(ws + WS_FW + (b*L_+l)*DL_ + c8 + 4);
    *(int4*)(smb + FW_B + l*272 + c8*2) = pack8(b0, b1);
  }
  if (t < 32) *(float4*)(sFs + t*4) = *(const float4*)(ws + WS_FS + b*DL_ + t*4);
  if (t < L_) sSb[t] = ws[WS_SB + b*L_ + t];
  __syncthreads();

  // ---------------- phase2: scores + softmax over L ------------------------
  for (int p = t; p < 32*L_; p += 256) {
    const int r = p / L_, l = p - r*L_;
    const int qs = (r & 7) << 4;
    const char* qrow = smb + SFCH_B + r*256;
    const short* kr = (const short*)(smb + KQ_B + l*272);
    float s = 0.f;
    #pragma unroll
    for (int k = 0; k < DL_; k += 8) {
      short8_t qv = *(const short8_t*)(qrow + ((k*2) ^ qs));
      short8_t kv = *(const short8_t*)(kr + k);
      s += b2f(qv[0])*b2f(kv[0]) + b2f(qv[1])*b2f(kv[1])
         + b2f(qv[2])*b2f(kv[2]) + b2f(qv[3])*b2f(kv[3])
         + b2f(qv[4])*b2f(kv[4]) + b2f(qv[5])*b2f(kv[5])
         + b2f(qv[6])*b2f(kv[6]) + b2f(qv[7])*b2f(kv[7]);
    }
    sAttn[r*21 + l] = (s + sSb[l]) * inv_sqrt_dl;
  }
  __syncthreads();
  if (t < 32) {
    float* srow = sAttn + t*21;
    float m = -1e30f;
    for (int l = 0; l < L_; ++l) m = fmaxf(m, srow[l]);
    float sum = 0.f;
    for (int l = 0; l < L_; ++l) { float e = __expf(srow[l]-m); srow[l] = e; sum += e; }
    float inv = 1.f/sum;
    for (int l = 0; l < L_; ++l) srow[l] *= inv;
  }
  __syncthreads();
  // ---------------- phase3: f_cq -> bf16 swizzled --------------------------
  for (int p = t; p < 1024; p += 256) {
    const int r = p >> 5, d4 = (p & 31) * 4;
    float ax = 0.f, ay = 0.f, az = 0.f, aw = 0.f;
    for (int l = 0; l < L_; ++l) {
      float a = sAttn[r*21 + l];
      ushort4 wv = *(const ushort4*)(smb + FW_B + l*272 + d4*2);
      ax += a*b2f((short)wv.x); ay += a*b2f((short)wv.y);
      az += a*b2f((short)wv.z); aw += a*b2f((short)wv.w);
    }
    const int rs = (r & 7) << 4;
    float4 fs4 = *(const float4*)(sFs + d4);
    ushort4 fh = *(const ushort4*)(smb + SFCH_B + r*256 + ((d4*2) ^ rs));
    ushort4 pk;
    pk.x = f2b(b2f((short)fh.x)*(ax+fs4.x));
    pk.y = f2b(b2f((short)fh.y)*(ay+fs4.y));
    pk.z = f2b(b2f((short)fh.z)*(az+fs4.z));
    pk.w = f2b(b2f((short)fh.w)*(aw+fs4.w));
    *(ushort4*)(smb + FCQ_B + r*256 + ((d4*2) ^ rs)) = pk;
  }
  __syncthreads();
  // ---------------- phase4: A_c + softmax over T3 --------------------------
  for (int p = t; p < 512; p += 256) {
    const int g = p >> 8, z = (p >> 4) & 15, wq = p & 15;
    const int xr = g*16 + z, yr = g*16 + wq;
    const char* xb = smb + FCQ_B + xr*256;
    const char* yb = smb + FCQ_B + yr*256;
    const int xs = (xr & 7) << 4, ys = (yr & 7) << 4;
    float s = 0.f;
    #pragma unroll
    for (int k = 0; k < DL_; k += 8) {
      short8_t xv = *(const short8_t*)(xb + ((k*2) ^ xs));
      short8_t yv = *(const short8_t*)(yb + ((k*2) ^ ys));
      s += b2f(xv[0])*b2f(yv[0]) + b2f(xv[1])*b2f(yv[1])
         + b2f(xv[2])*b2f(yv[2]) + b2f(xv[3])*b2f(yv[3])
         + b2f(xv[4])*b2f(yv[4]) + b2f(xv[5])*b2f(yv[5])
         + b2f(xv[6])*b2f(yv[6]) + b2f(xv[7])*b2f(yv[7]);
    }
    sAc[(g*16+z)*17 + wq] = s * inv_sqrt_dl;
  }
  __syncthreads();
  if (t < 32) {
    float* srow = sAc + t*17;
    float m = -1e30f;
    for (int wq = 0; wq < 16; ++wq) m = fmaxf(m, srow[wq]);
    float sum = 0.f;
    for (int wq = 0; wq < 16; ++wq) { float e = __expf(srow[wq]-m); srow[wq] = e; sum += e; }
    float inv = 1.f/sum;
    for (int wq = 0; wq < 16; ++wq) srow[wq] *= inv;
  }
  __syncthreads();
  // ---------------- phase5: f_cc_hat -> bf16 swizzled (over FCQ) -----------
  for (int p = t; p < 1024; p += 256) {
    const int r = p >> 5, d4 = (p & 31)*4;
    const int g = r >> 4, z = r & 15;
    float ax = 0.f, ay = 0.f, az = 0.f, aw = 0.f;
    #pragma unroll
    for (int wq = 0; wq < 16; ++wq) {
      float a = sAc[(g*16+z)*17 + wq];
      const int fr = g*16 + wq;
      ushort4 fv = *(const ushort4*)(smb + SFCH_B + fr*256 + ((d4*2) ^ ((fr & 7) << 4)));
      ax += a*b2f((short)fv.x); ay += a*b2f((short)fv.y);
      az += a*b2f((short)fv.z); aw += a*b2f((short)fv.w);
    }
    ushort4 pk;
    pk.x = f2b(ax); pk.y = f2b(ay); pk.z = f2b(az); pk.w = f2b(aw);
    *(ushort4*)(smb + FCQ_B + r*256 + ((d4*2) ^ ((r & 7) << 4))) = pk;
  }
  __syncthreads();

  // ---------------- up GEMM: staged Wu chunks + reg prefetch ---------------
  int4 wureg[4];
  auto load_wu = [&](int ch) {
    #pragma unroll
    for (int i = 0; i < 4; ++i) {
      int idx = t + i*256;
      wureg[i] = *(const int4*)(wub + (size_t)(ch*64 + (idx >> 4))*DL_ + (idx & 15)*8);
    }
  };
  load_wu(0);
  const int rr = wr + l15;
  const char* fcqrow = smb + FCQ_B + rr*256;
  const int xsw = (rr & 7) << 4;
  const int grow = row0 + rr;
  const size_t obase = (size_t)grow * D_;
  const size_t mbase = (size_t)(grow >> 4) * D_;
  for (int ch = 0; ch < 8; ++ch) {
    __syncthreads();
    #pragma unroll
    for (int i = 0; i < 4; ++i) {
      int idx = t + i*256;
      int d = idx >> 4, kb = (idx & 15) * 16;
      *(int4*)(smb + WU_B + d*256 + (kb ^ ((d & 7) << 4))) = wureg[i];
    }
    __syncthreads();
    if (ch < 7) load_wu(ch + 1);
    f32x4 uacc[2]; uacc[0] = z4; uacc[1] = z4;
    #pragma unroll
    for (int ks = 0; ks < 4; ++ks) {
      short8_t bfrag = *(const short8_t*)(fcqrow + ((ks*64 + l4*16) ^ xsw));
      #pragma unroll
      for (int cf = 0; cf < 2; ++cf) {
        const int dd = wc*32 + cf*16 + l15;
        short8_t afrag = *(const short8_t*)(smb + WU_B + dd*256 +
                          ((ks*64 + l4*16) ^ ((dd & 7) << 4)));
        uacc[cf] = __builtin_amdgcn_mfma_f32_16x16x32_bf16(afrag, bfrag, uacc[cf], 0, 0, 0);
      }
    }
    #pragma unroll
    for (int cf = 0; cf < 2; ++cf) {
      const int d0 = ch*64 + wc*32 + cf*16 + l4*4;
      float4 bias = *(const float4*)(bc_up + d0);
      float4 fs4 = *(const float4*)(f_s + (size_t)b*D_ + d0);
      float4 fm4 = *(const float4*)(f_m + mbase + d0);
      float4 fc4 = *(const float4*)(f_c + obase + d0);
      float4 o;
      o.x = uacc[cf][0] + bias.x + fc4.x + fm4.x/(1.f + __expf(-fm4.x*fs4.x));
      o.y = uacc[cf][1] + bias.y + fc4.y + fm4.y/(1.f + __expf(-fm4.y*fs4.y));
      o.z = uacc[cf][2] + bias.z + fc4.z + fm4.z/(1.f + __expf(-fm4.z*fs4.z));
      o.w = uacc[cf][3] + bias.w + fc4.w + fm4.w/(1.f + __expf(-fm4.w*fs4.w));
      *(float4*)(out + obase + d0) = o;
    }
  }
}

extern "C" void kernel_launch(void* const* d_in, const int* in_sizes, int n_in,
                              void* d_out, int out_size, void* d_ws, size_t ws_size,
                              hipStream_t stream) {
  (void)in_sizes; (void)n_in; (void)out_size; (void)ws_size;
  const float* f_c     = (const float*)d_in[0];
  const float* f_w     = (const float*)d_in[1];
  const float* f_s     = (const float*)d_in[2];
  const float* f_m     = (const float*)d_in[3];
  const float* Wc_down = (const float*)d_in[4];
  const float* bc_down = (const float*)d_in[5];
  const float* Ww      = (const float*)d_in[6];
  const float* bw      = (const float*)d_in[7];
  const float* Ws      = (const float*)d_in[8];
  const float* bs      = (const float*)d_in[9];
  const float* Wq      = (const float*)d_in[10];
  const float* bq      = (const float*)d_in[11];
  const float* Wk      = (const float*)d_in[12];
  const float* bk      = (const float*)d_in[13];
  const float* Wc_up   = (const float*)d_in[14];
  const float* bc_up   = (const float*)d_in[15];
  float* out = (float*)d_out;
  float* wsf = (float*)d_ws;
  unsigned short* wdb = (unsigned short*)(wsf + WS_WDB);
  unsigned short* wub = (unsigned short*)(wsf + WS_WUB);

  hipLaunchKernelGGL(k0_convert, dim3(128), dim3(256), 0, stream,
                     Wc_down, Wc_up, wdb, wub);
  hipLaunchKernelGGL(k1_small, dim3(B_*L_), dim3(128), 0, stream,
                     f_w, f_s, Ww, bw, Ws, bs, Wq, bq, Wk, bk, wsf);
  hipLaunchKernelGGL(k2_fused, dim3(M_/32), dim3(256), 0, stream,
                     f_c, wdb, wub, bc_down, bc_up, f_m, f_s, wsf, out);
}

// Round 5
// 269.585 us; speedup vs baseline: 1.8889x; 1.8889x over previous
//
#include <hip/hip_runtime.h>
#include <math.h>

#define B_ 8
#define T1_ 32
#define T2_ 32
#define T3_ 16
#define D_ 512
#define L_ 20
#define DL_ 128
#define M_ (B_*T1_*T2_*T3_)   // 131072

// workspace layout (float offsets)
#define WS_FW   0                      // B*L*DL
#define WS_KQ   20480                  // B*L*DL
#define WS_FS   40960                  // B*DL
#define WS_SB   41984                  // B*L
#define WS_WDB  42144                  // Wc_down bf16: 65536 ushort
#define WS_WUB  74912                  // Wc_up   bf16: 65536 ushort

typedef __attribute__((ext_vector_type(8))) short short8_t;
typedef __attribute__((ext_vector_type(4))) float f32x4;

__device__ __forceinline__ unsigned short f2b(float f) {
  unsigned int u = __float_as_uint(f);
  return (unsigned short)((u + 0x7fffu + ((u >> 16) & 1u)) >> 16);
}
__device__ __forceinline__ float b2f(short s) {
  return __uint_as_float(((unsigned)(unsigned short)s) << 16);
}
__device__ __forceinline__ int4 pack8(float4 a, float4 b) {
  int4 p;
  p.x = (int)f2b(a.x) | ((int)f2b(a.y) << 16);
  p.y = (int)f2b(a.z) | ((int)f2b(a.w) << 16);
  p.z = (int)f2b(b.x) | ((int)f2b(b.y) << 16);
  p.w = (int)f2b(b.z) | ((int)f2b(b.w) << 16);
  return p;
}

// ---------------------------------------------------------------------------
// K0: convert Wc_down [128][512] and Wc_up [512][128] fp32 -> bf16 in ws
// ---------------------------------------------------------------------------
__global__ __launch_bounds__(256) void k0_convert(
    const float* __restrict__ Wd, const float* __restrict__ Wu,
    unsigned short* __restrict__ wdb, unsigned short* __restrict__ wub) {
  int g = blockIdx.x * 256 + threadIdx.x;      // 0..32767
  if (g < 16384) {
    float4 v = ((const float4*)Wd)[g];
    ushort4 h; h.x = f2b(v.x); h.y = f2b(v.y); h.z = f2b(v.z); h.w = f2b(v.w);
    ((ushort4*)wdb)[g] = h;
  } else {
    int q = g - 16384;
    float4 v = ((const float4*)Wu)[q];
    ushort4 h; h.x = f2b(v.x); h.y = f2b(v.y); h.z = f2b(v.z); h.w = f2b(v.w);
    ((ushort4*)wub)[q] = h;
  }
}

// ---------------------------------------------------------------------------
// K1: tiny projections. grid = B*L blocks, 128 threads.
// ---------------------------------------------------------------------------
__global__ __launch_bounds__(128) void k1_small(
    const float* __restrict__ f_w, const float* __restrict__ f_s,
    const float* __restrict__ Ww, const float* __restrict__ bw,
    const float* __restrict__ Ws, const float* __restrict__ bs,
    const float* __restrict__ Wq, const float* __restrict__ bq,
    const float* __restrict__ Wk, const float* __restrict__ bk,
    float* __restrict__ ws) {
  const int bl = blockIdx.x;
  const int b = bl / L_, l = bl % L_;
  const int d = threadIdx.x;
  __shared__ float s_fw[DL_];
  __shared__ float s_k[DL_];
  {
    const float* x = f_w + (size_t)(b*L_+l)*D_;
    const float* w = Ww + (size_t)d*D_;
    float acc = 0.f;
    for (int i = 0; i < D_; i += 4)
      acc += x[i]*w[i] + x[i+1]*w[i+1] + x[i+2]*w[i+2] + x[i+3]*w[i+3];
    acc += bw[d];
    s_fw[d] = acc;
    ws[WS_FW + (b*L_+l)*DL_ + d] = acc;
  }
  if (l == 0) {
    const float* x = f_s + (size_t)b*D_;
    const float* w = Ws + (size_t)d*D_;
    float acc = 0.f;
    for (int i = 0; i < D_; i += 4)
      acc += x[i]*w[i] + x[i+1]*w[i+1] + x[i+2]*w[i+2] + x[i+3]*w[i+3];
    ws[WS_FS + b*DL_ + d] = acc + bs[d];
  }
  __syncthreads();
  {
    const float* w = Wk + (size_t)d*DL_;
    float acc = 0.f;
    for (int i = 0; i < DL_; ++i) acc += s_fw[i]*w[i];
    s_k[d] = acc + bk[d];
  }
  __syncthreads();
  {
    float acc = 0.f;
    for (int c = 0; c < DL_; ++c) acc += s_k[c] * Wq[c*DL_ + d];
    ws[WS_KQ + (b*L_+l)*DL_ + d] = acc;
  }
  if (d == 0) {
    float acc = 0.f;
    for (int c = 0; c < DL_; ++c) acc += bq[c]*s_k[c];
    ws[WS_SB + b*L_ + l] = acc;
  }
}

// ---------------------------------------------------------------------------
// K2: fused per 32-row tile. A=weights, B=activations (vectorized epilogue).
// Direct cooperative staging (round-2 style, NO reg-prefetch arrays/lambdas
// -- those spilled to scratch in round 4). 36.9 KB LDS -> 4 blocks/CU.
// ---------------------------------------------------------------------------
// LDS byte offsets
#define SFCH_B 0        // f_c_hat bf16 [32][256B], XOR-swizzled
#define FCQ_B  8192     // f_cq / f_cc_hat bf16 [32][256B], swizzled
#define WD_B   16384    // down: Wd chunk [128][128B]
#define FC_B   32768    // down: f_c chunk [32][128B]
#define KQ_B   16384    // mid: kq bf16 [20][272B]
#define FW_B   21824    // mid: fw bf16 [20][272B]
#define FS_B   27264    // mid: f_s_hat f32 [128]
#define SB_B   27776    // mid: sb f32 [20]
#define ATTN_B 27904    // mid: attn f32 [32][21]
#define AC_B   30592    // mid: A_c f32 [32][17]
#define WU_B   16384    // up: Wu chunk [64][256B]
#define SMEM_B 36864

__global__ __launch_bounds__(256, 4) void k2_fused(
    const float* __restrict__ f_c, const unsigned short* __restrict__ wdb,
    const unsigned short* __restrict__ wub,
    const float* __restrict__ bc_down, const float* __restrict__ bc_up,
    const float* __restrict__ f_m, const float* __restrict__ f_s,
    const float* __restrict__ ws, float* __restrict__ out) {
  __shared__ __align__(16) char smb[SMEM_B];
  float* sAttn = (float*)(smb + ATTN_B);
  float* sAc   = (float*)(smb + AC_B);
  float* sFs   = (float*)(smb + FS_B);
  float* sSb   = (float*)(smb + SB_B);

  const int t = threadIdx.x;
  const int row0 = blockIdx.x * 32;
  const int b = row0 >> 14;
  const int lane = t & 63, w = t >> 6;
  const int l15 = lane & 15, l4 = lane >> 4;
  const int wr = (w & 1) * 16;        // activation-row group
  const int wc = w >> 1;              // d-col group
  const float inv_sqrt_dl = 0.08838834764831843f;
  const f32x4 z4 = {0.f, 0.f, 0.f, 0.f};
  const int sd_r = t >> 3, sd_k8 = (t & 7) * 8;   // f_c staging coords

  // ---------------- down GEMM: direct cooperative staging ------------------
  f32x4 dacc[4];
  #pragma unroll
  for (int cf = 0; cf < 4; ++cf) dacc[cf] = z4;

  for (int kc = 0; kc < D_; kc += 64) {
    // stage Wd chunk [128 rows][64 k] bf16, XOR-swizzled
    #pragma unroll
    for (int i = 0; i < 4; ++i) {
      int idx = t + i*256;
      int d = idx >> 3, kb = idx & 7;
      *(int4*)(smb + WD_B + d*128 + ((kb*16) ^ ((d & 7) << 4))) =
        *(const int4*)(wdb + (size_t)d*D_ + kc + kb*8);
    }
    // stage f_c chunk [32 rows][64 k] fp32 -> bf16, swizzled
    {
      const float* src = f_c + (size_t)(row0 + sd_r)*D_ + kc + sd_k8;
      float4 v0 = *(const float4*)src;
      float4 v1 = *(const float4*)(src + 4);
      int4 pk = pack8(v0, v1);
      *(int4*)(smb + FC_B + sd_r*128 + ((sd_k8*2) ^ ((sd_r & 7) << 4))) = pk;
    }
    __syncthreads();
    #pragma unroll
    for (int ks = 0; ks < 2; ++ks) {
      const int rr = wr + l15;
      short8_t bfrag = *(const short8_t*)(smb + FC_B + rr*128 +
                        ((ks*64 + l4*16) ^ ((rr & 7) << 4)));
      #pragma unroll
      for (int cf = 0; cf < 4; ++cf) {
        const int d = wc*64 + cf*16 + l15;
        short8_t afrag = *(const short8_t*)(smb + WD_B + d*128 +
                          ((ks*64 + l4*16) ^ ((d & 7) << 4)));
        dacc[cf] = __builtin_amdgcn_mfma_f32_16x16x32_bf16(afrag, bfrag, dacc[cf], 0, 0, 0);
      }
    }
    __syncthreads();
  }
  // writeout f_c_hat: lane holds row rr = wr+l15, d0..d0+3 consecutive
  {
    const int rr = wr + l15;
    const int rs = (rr & 7) << 4;
    #pragma unroll
    for (int cf = 0; cf < 4; ++cf) {
      const int d0 = wc*64 + cf*16 + l4*4;
      float4 bias = *(const float4*)(bc_down + d0);
      ushort4 pk;
      pk.x = f2b(dacc[cf][0] + bias.x); pk.y = f2b(dacc[cf][1] + bias.y);
      pk.z = f2b(dacc[cf][2] + bias.z); pk.w = f2b(dacc[cf][3] + bias.w);
      *(ushort4*)(smb + SFCH_B + rr*256 + ((d0*2) ^ rs)) = pk;
    }
  }
  // stage per-batch smalls (down staging region becomes mid region)
  for (int p = t; p < L_*16; p += 256) {
    const int l = p >> 4, c8 = (p & 15) * 8;
    float4 a0 = *(const float4*)(ws + WS_KQ + (b*L_+l)*DL_ + c8);
    float4 a1 = *(const float4*)(ws + WS_KQ + (b*L_+l)*DL_ + c8 + 4);
    *(int4*)(smb + KQ_B + l*272 + c8*2) = pack8(a0, a1);
    float4 b0 = *(const float4*)(ws + WS_FW + (b*L_+l)*DL_ + c8);
    float4 b1 = *(const float4*)(ws + WS_FW + (b*L_+l)*DL_ + c8 + 4);
    *(int4*)(smb + FW_B + l*272 + c8*2) = pack8(b0, b1);
  }
  if (t < 32) *(float4*)(sFs + t*4) = *(const float4*)(ws + WS_FS + b*DL_ + t*4);
  if (t < L_) sSb[t] = ws[WS_SB + b*L_ + t];
  __syncthreads();

  // ---------------- phase2: scores + softmax over L ------------------------
  for (int p = t; p < 32*L_; p += 256) {
    const int r = p / L_, l = p - r*L_;
    const int qs = (r & 7) << 4;
    const char* qrow = smb + SFCH_B + r*256;
    const short* kr = (const short*)(smb + KQ_B + l*272);
    float s = 0.f;
    #pragma unroll
    for (int k = 0; k < DL_; k += 8) {
      short8_t qv = *(const short8_t*)(qrow + ((k*2) ^ qs));
      short8_t kv = *(const short8_t*)(kr + k);
      s += b2f(qv[0])*b2f(kv[0]) + b2f(qv[1])*b2f(kv[1])
         + b2f(qv[2])*b2f(kv[2]) + b2f(qv[3])*b2f(kv[3])
         + b2f(qv[4])*b2f(kv[4]) + b2f(qv[5])*b2f(kv[5])
         + b2f(qv[6])*b2f(kv[6]) + b2f(qv[7])*b2f(kv[7]);
    }
    sAttn[r*21 + l] = (s + sSb[l]) * inv_sqrt_dl;
  }
  __syncthreads();
  if (t < 32) {
    float* srow = sAttn + t*21;
    float m = -1e30f;
    for (int l = 0; l < L_; ++l) m = fmaxf(m, srow[l]);
    float sum = 0.f;
    for (int l = 0; l < L_; ++l) { float e = __expf(srow[l]-m); srow[l] = e; sum += e; }
    float inv = 1.f/sum;
    for (int l = 0; l < L_; ++l) srow[l] *= inv;
  }
  __syncthreads();
  // ---------------- phase3: f_cq -> bf16 swizzled --------------------------
  for (int p = t; p < 1024; p += 256) {
    const int r = p >> 5, d4 = (p & 31) * 4;
    float ax = 0.f, ay = 0.f, az = 0.f, aw = 0.f;
    for (int l = 0; l < L_; ++l) {
      float a = sAttn[r*21 + l];
      ushort4 wv = *(const ushort4*)(smb + FW_B + l*272 + d4*2);
      ax += a*b2f((short)wv.x); ay += a*b2f((short)wv.y);
      az += a*b2f((short)wv.z); aw += a*b2f((short)wv.w);
    }
    const int rs = (r & 7) << 4;
    float4 fs4 = *(const float4*)(sFs + d4);
    ushort4 fh = *(const ushort4*)(smb + SFCH_B + r*256 + ((d4*2) ^ rs));
    ushort4 pk;
    pk.x = f2b(b2f((short)fh.x)*(ax+fs4.x));
    pk.y = f2b(b2f((short)fh.y)*(ay+fs4.y));
    pk.z = f2b(b2f((short)fh.z)*(az+fs4.z));
    pk.w = f2b(b2f((short)fh.w)*(aw+fs4.w));
    *(ushort4*)(smb + FCQ_B + r*256 + ((d4*2) ^ rs)) = pk;
  }
  __syncthreads();
  // ---------------- phase4: A_c + softmax over T3 --------------------------
  for (int p = t; p < 512; p += 256) {
    const int g = p >> 8, z = (p >> 4) & 15, wq = p & 15;
    const int xr = g*16 + z, yr = g*16 + wq;
    const char* xb = smb + FCQ_B + xr*256;
    const char* yb = smb + FCQ_B + yr*256;
    const int xs = (xr & 7) << 4, ys = (yr & 7) << 4;
    float s = 0.f;
    #pragma unroll
    for (int k = 0; k < DL_; k += 8) {
      short8_t xv = *(const short8_t*)(xb + ((k*2) ^ xs));
      short8_t yv = *(const short8_t*)(yb + ((k*2) ^ ys));
      s += b2f(xv[0])*b2f(yv[0]) + b2f(xv[1])*b2f(yv[1])
         + b2f(xv[2])*b2f(yv[2]) + b2f(xv[3])*b2f(yv[3])
         + b2f(xv[4])*b2f(yv[4]) + b2f(xv[5])*b2f(yv[5])
         + b2f(xv[6])*b2f(yv[6]) + b2f(xv[7])*b2f(yv[7]);
    }
    sAc[(g*16+z)*17 + wq] = s * inv_sqrt_dl;
  }
  __syncthreads();
  if (t < 32) {
    float* srow = sAc + t*17;
    float m = -1e30f;
    for (int wq = 0; wq < 16; ++wq) m = fmaxf(m, srow[wq]);
    float sum = 0.f;
    for (int wq = 0; wq < 16; ++wq) { float e = __expf(srow[wq]-m); srow[wq] = e; sum += e; }
    float inv = 1.f/sum;
    for (int wq = 0; wq < 16; ++wq) srow[wq] *= inv;
  }
  __syncthreads();
  // ---------------- phase5: f_cc_hat -> bf16 swizzled (over FCQ) -----------
  for (int p = t; p < 1024; p += 256) {
    const int r = p >> 5, d4 = (p & 31)*4;
    const int g = r >> 4, z = r & 15;
    float ax = 0.f, ay = 0.f, az = 0.f, aw = 0.f;
    #pragma unroll
    for (int wq = 0; wq < 16; ++wq) {
      float a = sAc[(g*16+z)*17 + wq];
      const int fr = g*16 + wq;
      ushort4 fv = *(const ushort4*)(smb + SFCH_B + fr*256 + ((d4*2) ^ ((fr & 7) << 4)));
      ax += a*b2f((short)fv.x); ay += a*b2f((short)fv.y);
      az += a*b2f((short)fv.z); aw += a*b2f((short)fv.w);
    }
    ushort4 pk;
    pk.x = f2b(ax); pk.y = f2b(ay); pk.z = f2b(az); pk.w = f2b(aw);
    *(ushort4*)(smb + FCQ_B + r*256 + ((d4*2) ^ ((r & 7) << 4))) = pk;
  }
  __syncthreads();

  // ---------------- up GEMM: direct cooperative staging --------------------
  const int rr = wr + l15;
  const char* fcqrow = smb + FCQ_B + rr*256;
  const int xsw = (rr & 7) << 4;
  const int grow = row0 + rr;
  const size_t obase = (size_t)grow * D_;
  const size_t mbase = (size_t)(grow >> 4) * D_;
  for (int ch = 0; ch < 8; ++ch) {
    // stage Wu chunk [64 d-rows][128 k] bf16, swizzled
    #pragma unroll
    for (int i = 0; i < 4; ++i) {
      int idx = t + i*256;
      int d = idx >> 4, kb = idx & 15;
      *(int4*)(smb + WU_B + d*256 + ((kb*16) ^ ((d & 7) << 4))) =
        *(const int4*)(wub + (size_t)(ch*64 + d)*DL_ + kb*8);
    }
    __syncthreads();
    f32x4 uacc[2]; uacc[0] = z4; uacc[1] = z4;
    #pragma unroll
    for (int ks = 0; ks < 4; ++ks) {
      short8_t bfrag = *(const short8_t*)(fcqrow + ((ks*64 + l4*16) ^ xsw));
      #pragma unroll
      for (int cf = 0; cf < 2; ++cf) {
        const int dd = wc*32 + cf*16 + l15;
        short8_t afrag = *(const short8_t*)(smb + WU_B + dd*256 +
                          ((ks*64 + l4*16) ^ ((dd & 7) << 4)));
        uacc[cf] = __builtin_amdgcn_mfma_f32_16x16x32_bf16(afrag, bfrag, uacc[cf], 0, 0, 0);
      }
    }
    #pragma unroll
    for (int cf = 0; cf < 2; ++cf) {
      const int d0 = ch*64 + wc*32 + cf*16 + l4*4;
      float4 bias = *(const float4*)(bc_up + d0);
      float4 fs4 = *(const float4*)(f_s + (size_t)b*D_ + d0);
      float4 fm4 = *(const float4*)(f_m + mbase + d0);
      float4 fc4 = *(const float4*)(f_c + obase + d0);
      float4 o;
      o.x = uacc[cf][0] + bias.x + fc4.x + fm4.x/(1.f + __expf(-fm4.x*fs4.x));
      o.y = uacc[cf][1] + bias.y + fc4.y + fm4.y/(1.f + __expf(-fm4.y*fs4.y));
      o.z = uacc[cf][2] + bias.z + fc4.z + fm4.z/(1.f + __expf(-fm4.z*fs4.z));
      o.w = uacc[cf][3] + bias.w + fc4.w + fm4.w/(1.f + __expf(-fm4.w*fs4.w));
      *(float4*)(out + obase + d0) = o;
    }
    __syncthreads();
  }
}

extern "C" void kernel_launch(void* const* d_in, const int* in_sizes, int n_in,
                              void* d_out, int out_size, void* d_ws, size_t ws_size,
                              hipStream_t stream) {
  (void)in_sizes; (void)n_in; (void)out_size; (void)ws_size;
  const float* f_c     = (const float*)d_in[0];
  const float* f_w     = (const float*)d_in[1];
  const float* f_s     = (const float*)d_in[2];
  const float* f_m     = (const float*)d_in[3];
  const float* Wc_down = (const float*)d_in[4];
  const float* bc_down = (const float*)d_in[5];
  const float* Ww      = (const float*)d_in[6];
  const float* bw      = (const float*)d_in[7];
  const float* Ws      = (const float*)d_in[8];
  const float* bs      = (const float*)d_in[9];
  const float* Wq      = (const float*)d_in[10];
  const float* bq      = (const float*)d_in[11];
  const float* Wk      = (const float*)d_in[12];
  const float* bk      = (const float*)d_in[13];
  const float* Wc_up   = (const float*)d_in[14];
  const float* bc_up   = (const float*)d_in[15];
  float* out = (float*)d_out;
  float* wsf = (float*)d_ws;
  unsigned short* wdb = (unsigned short*)(wsf + WS_WDB);
  unsigned short* wub = (unsigned short*)(wsf + WS_WUB);

  hipLaunchKernelGGL(k0_convert, dim3(128), dim3(256), 0, stream,
                     Wc_down, Wc_up, wdb, wub);
  hipLaunchKernelGGL(k1_small, dim3(B_*L_), dim3(128), 0, stream,
                     f_w, f_s, Ww, bw, Ws, bs, Wq, bq, Wk, bk, wsf);
  hipLaunchKernelGGL(k2_fused, dim3(M_/32), dim3(256), 0, stream,
                     f_c, wdb, wub, bc_down, bc_up, f_m, f_s, wsf, out);
}

// Round 6
// 252.902 us; speedup vs baseline: 2.0135x; 1.0660x over previous
//
#include <hip/hip_runtime.h>
#include <math.h>

#define B_ 8
#define T1_ 32
#define T2_ 32
#define T3_ 16
#define D_ 512
#define L_ 20
#define DL_ 128
#define M_ (B_*T1_*T2_*T3_)   // 131072

// workspace layout (float offsets)
#define WS_FW   0                      // B*L*DL
#define WS_KQ   20480                  // B*L*DL
#define WS_FS   40960                  // B*DL
#define WS_SB   41984                  // B*L
#define WS_WDB  42144                  // Wc_down bf16: 65536 ushort
#define WS_WUB  74912                  // Wc_up   bf16: 65536 ushort

typedef __attribute__((ext_vector_type(8))) short short8_t;
typedef __attribute__((ext_vector_type(4))) float f32x4;

__device__ __forceinline__ unsigned short f2b(float f) {
  unsigned int u = __float_as_uint(f);
  return (unsigned short)((u + 0x7fffu + ((u >> 16) & 1u)) >> 16);
}
__device__ __forceinline__ float b2f(short s) {
  return __uint_as_float(((unsigned)(unsigned short)s) << 16);
}
__device__ __forceinline__ int4 pack8(float4 a, float4 b) {
  int4 p;
  p.x = (int)f2b(a.x) | ((int)f2b(a.y) << 16);
  p.y = (int)f2b(a.z) | ((int)f2b(a.w) << 16);
  p.z = (int)f2b(b.x) | ((int)f2b(b.y) << 16);
  p.w = (int)f2b(b.z) | ((int)f2b(b.w) << 16);
  return p;
}

// ---------------------------------------------------------------------------
// K0: convert Wc_down [128][512] and Wc_up [512][128] fp32 -> bf16 in ws
// ---------------------------------------------------------------------------
__global__ __launch_bounds__(256) void k0_convert(
    const float* __restrict__ Wd, const float* __restrict__ Wu,
    unsigned short* __restrict__ wdb, unsigned short* __restrict__ wub) {
  int g = blockIdx.x * 256 + threadIdx.x;      // 0..32767
  if (g < 16384) {
    float4 v = ((const float4*)Wd)[g];
    ushort4 h; h.x = f2b(v.x); h.y = f2b(v.y); h.z = f2b(v.z); h.w = f2b(v.w);
    ((ushort4*)wdb)[g] = h;
  } else {
    int q = g - 16384;
    float4 v = ((const float4*)Wu)[q];
    ushort4 h; h.x = f2b(v.x); h.y = f2b(v.y); h.z = f2b(v.z); h.w = f2b(v.w);
    ((ushort4*)wub)[q] = h;
  }
}

// ---------------------------------------------------------------------------
// K1: tiny projections. grid = B*L blocks, 128 threads.
// ---------------------------------------------------------------------------
__global__ __launch_bounds__(128) void k1_small(
    const float* __restrict__ f_w, const float* __restrict__ f_s,
    const float* __restrict__ Ww, const float* __restrict__ bw,
    const float* __restrict__ Ws, const float* __restrict__ bs,
    const float* __restrict__ Wq, const float* __restrict__ bq,
    const float* __restrict__ Wk, const float* __restrict__ bk,
    float* __restrict__ ws) {
  const int bl = blockIdx.x;
  const int b = bl / L_, l = bl % L_;
  const int d = threadIdx.x;
  __shared__ float s_fw[DL_];
  __shared__ float s_k[DL_];
  {
    const float* x = f_w + (size_t)(b*L_+l)*D_;
    const float* w = Ww + (size_t)d*D_;
    float acc = 0.f;
    for (int i = 0; i < D_; i += 4)
      acc += x[i]*w[i] + x[i+1]*w[i+1] + x[i+2]*w[i+2] + x[i+3]*w[i+3];
    acc += bw[d];
    s_fw[d] = acc;
    ws[WS_FW + (b*L_+l)*DL_ + d] = acc;
  }
  if (l == 0) {
    const float* x = f_s + (size_t)b*D_;
    const float* w = Ws + (size_t)d*D_;
    float acc = 0.f;
    for (int i = 0; i < D_; i += 4)
      acc += x[i]*w[i] + x[i+1]*w[i+1] + x[i+2]*w[i+2] + x[i+3]*w[i+3];
    ws[WS_FS + b*DL_ + d] = acc + bs[d];
  }
  __syncthreads();
  {
    const float* w = Wk + (size_t)d*DL_;
    float acc = 0.f;
    for (int i = 0; i < DL_; ++i) acc += s_fw[i]*w[i];
    s_k[d] = acc + bk[d];
  }
  __syncthreads();
  {
    float acc = 0.f;
    for (int c = 0; c < DL_; ++c) acc += s_k[c] * Wq[c*DL_ + d];
    ws[WS_KQ + (b*L_+l)*DL_ + d] = acc;
  }
  if (d == 0) {
    float acc = 0.f;
    for (int c = 0; c < DL_; ++c) acc += bq[c]*s_k[c];
    ws[WS_SB + b*L_ + l] = acc;
  }
}

// ---------------------------------------------------------------------------
// K2: fused per 32-row tile. All matmul-shaped phases on MFMA.
// 40 KB LDS -> 4 blocks/CU.
// ---------------------------------------------------------------------------
// LDS byte offsets
#define SFCH_B 0        // f_c_hat bf16 [32][256B], XOR-swizzled ((r&7)<<4)
#define FCQ_B  8192     // f_cq / f_cc_hat bf16 [32][256B], swizzled
#define WD_B   16384    // down: Wd chunk [128][128B] swz
#define FC_B   32768    // down: f_c chunk [32][128B] swz
#define KQ_B   16384    // mid: kq bf16 [32][256B] swz, rows>=20 zero
#define FWT_B  24576    // mid: fw^T bf16 [128][64B] swz ((d&3)<<4)
#define ATB_B  32768    // mid: attn bf16 [32][128B] swz, k>=20 zero
#define FS_B   36864    // mid: f_s_hat f32 [128]
#define SB_B   37376    // mid: sb f32 [20]
#define ATTN_B 37504    // mid: attn f32 [32][21]  (aliased by sAc later)
#define AC_B   37504    // mid: A_c f32 [32][17]   (alias: disjoint in time)
#define WU_B   16384    // up: Wu chunk [64][256B] swz
#define SMEM_B 40960

__global__ __launch_bounds__(256, 4) void k2_fused(
    const float* __restrict__ f_c, const unsigned short* __restrict__ wdb,
    const unsigned short* __restrict__ wub,
    const float* __restrict__ bc_down, const float* __restrict__ bc_up,
    const float* __restrict__ f_m, const float* __restrict__ f_s,
    const float* __restrict__ ws, float* __restrict__ out) {
  __shared__ __align__(16) char smb[SMEM_B];
  float* sAttn = (float*)(smb + ATTN_B);
  float* sAc   = (float*)(smb + AC_B);
  float* sFs   = (float*)(smb + FS_B);
  float* sSb   = (float*)(smb + SB_B);

  const int t = threadIdx.x;
  const int row0 = blockIdx.x * 32;
  const int b = row0 >> 14;
  const int lane = t & 63, w = t >> 6;
  const int l15 = lane & 15, l4 = lane >> 4;
  const int wr = (w & 1) * 16;        // activation-row group
  const int wc = w >> 1;              // d-col group
  const float inv_sqrt_dl = 0.08838834764831843f;
  const f32x4 z4 = {0.f, 0.f, 0.f, 0.f};
  const int sd_r = t >> 3, sd_k8 = (t & 7) * 8;   // f_c staging coords

  // ---------------- down GEMM: direct cooperative staging ------------------
  f32x4 dacc[4];
  #pragma unroll
  for (int cf = 0; cf < 4; ++cf) dacc[cf] = z4;

  for (int kc = 0; kc < D_; kc += 64) {
    #pragma unroll
    for (int i = 0; i < 4; ++i) {
      int idx = t + i*256;
      int d = idx >> 3, kb = idx & 7;
      *(int4*)(smb + WD_B + d*128 + ((kb*16) ^ ((d & 7) << 4))) =
        *(const int4*)(wdb + (size_t)d*D_ + kc + kb*8);
    }
    {
      const float* src = f_c + (size_t)(row0 + sd_r)*D_ + kc + sd_k8;
      float4 v0 = *(const float4*)src;
      float4 v1 = *(const float4*)(src + 4);
      int4 pk = pack8(v0, v1);
      *(int4*)(smb + FC_B + sd_r*128 + ((sd_k8*2) ^ ((sd_r & 7) << 4))) = pk;
    }
    __syncthreads();
    #pragma unroll
    for (int ks = 0; ks < 2; ++ks) {
      const int rr = wr + l15;
      short8_t bfrag = *(const short8_t*)(smb + FC_B + rr*128 +
                        ((ks*64 + l4*16) ^ ((rr & 7) << 4)));
      #pragma unroll
      for (int cf = 0; cf < 4; ++cf) {
        const int d = wc*64 + cf*16 + l15;
        short8_t afrag = *(const short8_t*)(smb + WD_B + d*128 +
                          ((ks*64 + l4*16) ^ ((d & 7) << 4)));
        dacc[cf] = __builtin_amdgcn_mfma_f32_16x16x32_bf16(afrag, bfrag, dacc[cf], 0, 0, 0);
      }
    }
    __syncthreads();
  }
  // writeout f_c_hat (bf16, swizzled): lane holds row rr, 4 consecutive d
  {
    const int rr = wr + l15;
    const int rs = (rr & 7) << 4;
    #pragma unroll
    for (int cf = 0; cf < 4; ++cf) {
      const int d0 = wc*64 + cf*16 + l4*4;
      float4 bias = *(const float4*)(bc_down + d0);
      ushort4 pk;
      pk.x = f2b(dacc[cf][0] + bias.x); pk.y = f2b(dacc[cf][1] + bias.y);
      pk.z = f2b(dacc[cf][2] + bias.z); pk.w = f2b(dacc[cf][3] + bias.w);
      *(ushort4*)(smb + SFCH_B + rr*256 + ((d0*2) ^ rs)) = pk;
    }
  }
  // stage kq [32][256B] swz (rows >= 20 zero)
  for (int p = t; p < 32*16; p += 256) {
    const int l = p >> 4, k8 = (p & 15) * 8;
    int4 v = {0,0,0,0};
    if (l < L_) {
      float4 a0 = *(const float4*)(ws + WS_KQ + (b*L_+l)*DL_ + k8);
      float4 a1 = *(const float4*)(ws + WS_KQ + (b*L_+l)*DL_ + k8 + 4);
      v = pack8(a0, a1);
    }
    *(int4*)(smb + KQ_B + l*256 + ((k8*2) ^ ((l & 7) << 4))) = v;
  }
  // stage fw^T [128 d][64B] swz: fwT[d][l] = fw[l][d], l >= 20 zero
  for (int p = t; p < 512; p += 256) {
    const int d = p >> 2, l8 = (p & 3) * 8;
    float vv[8];
    #pragma unroll
    for (int e = 0; e < 8; ++e) {
      const int l = l8 + e;
      vv[e] = (l < L_) ? ws[WS_FW + (b*L_+l)*DL_ + d] : 0.f;
    }
    int4 v;
    v.x = (int)f2b(vv[0]) | ((int)f2b(vv[1]) << 16);
    v.y = (int)f2b(vv[2]) | ((int)f2b(vv[3]) << 16);
    v.z = (int)f2b(vv[4]) | ((int)f2b(vv[5]) << 16);
    v.w = (int)f2b(vv[6]) | ((int)f2b(vv[7]) << 16);
    *(int4*)(smb + FWT_B + d*64 + ((l8*2) ^ ((d & 3) << 4))) = v;
  }
  if (t < 32) *(float4*)(sFs + t*4) = *(const float4*)(ws + WS_FS + b*DL_ + t*4);
  if (t < L_) sSb[t] = ws[WS_SB + b*L_ + t];
  __syncthreads();

  // ---------------- phase2: scores via MFMA --------------------------------
  {
    const int lt = w & 1, rt = w >> 1;
    const int arow = lt*16 + l15;       // kq row (l index)
    const int brow = rt*16 + l15;       // f_c_hat row (r index)
    f32x4 sacc = z4;
    #pragma unroll
    for (int ks = 0; ks < 4; ++ks) {
      short8_t af = *(const short8_t*)(smb + KQ_B + arow*256 +
                     ((ks*64 + l4*16) ^ ((arow & 7) << 4)));
      short8_t bf = *(const short8_t*)(smb + SFCH_B + brow*256 +
                     ((ks*64 + l4*16) ^ ((brow & 7) << 4)));
      sacc = __builtin_amdgcn_mfma_f32_16x16x32_bf16(af, bf, sacc, 0, 0, 0);
    }
    const int r2 = rt*16 + l15;
    #pragma unroll
    for (int reg = 0; reg < 4; ++reg) {
      const int lval = lt*16 + l4*4 + reg;
      if (lval < L_) sAttn[r2*21 + lval] = (sacc[reg] + sSb[lval]) * inv_sqrt_dl;
    }
  }
  __syncthreads();
  if (t < 32) {                          // softmax over L (20-wide, cheap)
    float* srow = sAttn + t*21;
    float m = -1e30f;
    for (int l = 0; l < L_; ++l) m = fmaxf(m, srow[l]);
    float sum = 0.f;
    for (int l = 0; l < L_; ++l) { float e = __expf(srow[l]-m); srow[l] = e; sum += e; }
    float inv = 1.f/sum;
    for (int l = 0; l < L_; ++l) srow[l] *= inv;
  }
  __syncthreads();
  // pack attn -> bf16 B-operand [32][128B] swz (k >= 20 zero)
  {
    const int r = t >> 3, k8 = (t & 7) * 8;
    int4 v = {0,0,0,0};
    if (k8 < L_) {
      float vv[8];
      #pragma unroll
      for (int e = 0; e < 8; ++e) {
        const int l = k8 + e;
        vv[e] = (l < L_) ? sAttn[r*21 + l] : 0.f;
      }
      v.x = (int)f2b(vv[0]) | ((int)f2b(vv[1]) << 16);
      v.y = (int)f2b(vv[2]) | ((int)f2b(vv[3]) << 16);
      v.z = (int)f2b(vv[4]) | ((int)f2b(vv[5]) << 16);
      v.w = (int)f2b(vv[6]) | ((int)f2b(vv[7]) << 16);
    }
    *(int4*)(smb + ATB_B + r*128 + ((k8*2) ^ ((r & 7) << 4))) = v;
  }
  __syncthreads();
  // ---------------- phase3: f_caq via MFMA, gate, -> FCQ bf16 --------------
  {
    f32x4 cacc[2][2];
    cacc[0][0] = z4; cacc[0][1] = z4; cacc[1][0] = z4; cacc[1][1] = z4;
    #pragma unroll
    for (int dt = 0; dt < 2; ++dt) {
      const int arow = (w*2 + dt)*16 + l15;   // fwT row (d index)
      short8_t af = *(const short8_t*)(smb + FWT_B + arow*64 +
                     ((l4*16) ^ ((arow & 3) << 4)));
      #pragma unroll
      for (int rt = 0; rt < 2; ++rt) {
        const int brow = rt*16 + l15;          // attn row (r index)
        short8_t bf = *(const short8_t*)(smb + ATB_B + brow*128 +
                       ((l4*16) ^ ((brow & 7) << 4)));
        cacc[dt][rt] = __builtin_amdgcn_mfma_f32_16x16x32_bf16(af, bf, cacc[dt][rt], 0, 0, 0);
      }
    }
    #pragma unroll
    for (int dt = 0; dt < 2; ++dt)
    #pragma unroll
    for (int rt = 0; rt < 2; ++rt) {
      const int d0 = (w*2 + dt)*16 + l4*4;
      const int r = rt*16 + l15;
      const int rs = (r & 7) << 4;
      float4 fs4 = *(const float4*)(sFs + d0);
      ushort4 fh = *(const ushort4*)(smb + SFCH_B + r*256 + ((d0*2) ^ rs));
      ushort4 pk;
      pk.x = f2b(b2f((short)fh.x)*(cacc[dt][rt][0] + fs4.x));
      pk.y = f2b(b2f((short)fh.y)*(cacc[dt][rt][1] + fs4.y));
      pk.z = f2b(b2f((short)fh.z)*(cacc[dt][rt][2] + fs4.z));
      pk.w = f2b(b2f((short)fh.w)*(cacc[dt][rt][3] + fs4.w));
      *(ushort4*)(smb + FCQ_B + r*256 + ((d0*2) ^ rs)) = pk;
    }
  }
  __syncthreads();
  // ---------------- phase4: A_c via Gram MFMA + wave-parallel softmax ------
  if (w < 2) {
    const int zrow = w*16 + l15;
    f32x4 pacc = z4;
    #pragma unroll
    for (int ks = 0; ks < 4; ++ks) {
      short8_t fq = *(const short8_t*)(smb + FCQ_B + zrow*256 +
                     ((ks*64 + l4*16) ^ ((zrow & 7) << 4)));
      pacc = __builtin_amdgcn_mfma_f32_16x16x32_bf16(fq, fq, pacc, 0, 0, 0);
    }
    float p0[4], m[4], e[4], s[4];
    #pragma unroll
    for (int reg = 0; reg < 4; ++reg) p0[reg] = pacc[reg] * inv_sqrt_dl;
    #pragma unroll
    for (int reg = 0; reg < 4; ++reg) {
      m[reg] = p0[reg];
      m[reg] = fmaxf(m[reg], __shfl_xor(m[reg], 1));
      m[reg] = fmaxf(m[reg], __shfl_xor(m[reg], 2));
      m[reg] = fmaxf(m[reg], __shfl_xor(m[reg], 4));
      m[reg] = fmaxf(m[reg], __shfl_xor(m[reg], 8));
      e[reg] = __expf(p0[reg] - m[reg]);
      s[reg] = e[reg];
      s[reg] += __shfl_xor(s[reg], 1);
      s[reg] += __shfl_xor(s[reg], 2);
      s[reg] += __shfl_xor(s[reg], 4);
      s[reg] += __shfl_xor(s[reg], 8);
    }
    #pragma unroll
    for (int reg = 0; reg < 4; ++reg)
      sAc[(w*16 + l4*4 + reg)*17 + l15] = e[reg] / s[reg];
  }
  __syncthreads();
  // ---------------- phase5: f_cc_hat -> bf16 swizzled (over FCQ) -----------
  for (int p = t; p < 1024; p += 256) {
    const int r = p >> 5, d4 = (p & 31)*4;
    const int g = r >> 4, z = r & 15;
    float ax = 0.f, ay = 0.f, az = 0.f, aw = 0.f;
    #pragma unroll
    for (int wq = 0; wq < 16; ++wq) {
      float a = sAc[(g*16+z)*17 + wq];
      const int fr = g*16 + wq;
      ushort4 fv = *(const ushort4*)(smb + SFCH_B + fr*256 + ((d4*2) ^ ((fr & 7) << 4)));
      ax += a*b2f((short)fv.x); ay += a*b2f((short)fv.y);
      az += a*b2f((short)fv.z); aw += a*b2f((short)fv.w);
    }
    ushort4 pk;
    pk.x = f2b(ax); pk.y = f2b(ay); pk.z = f2b(az); pk.w = f2b(aw);
    *(ushort4*)(smb + FCQ_B + r*256 + ((d4*2) ^ ((r & 7) << 4))) = pk;
  }
  __syncthreads();

  // ---------------- up GEMM: direct cooperative staging --------------------
  const int rr = wr + l15;
  const char* fcqrow = smb + FCQ_B + rr*256;
  const int xsw = (rr & 7) << 4;
  const int grow = row0 + rr;
  const size_t obase = (size_t)grow * D_;
  const size_t mbase = (size_t)(grow >> 4) * D_;
  for (int ch = 0; ch < 8; ++ch) {
    #pragma unroll
    for (int i = 0; i < 4; ++i) {
      int idx = t + i*256;
      int d = idx >> 4, kb = idx & 15;
      *(int4*)(smb + WU_B + d*256 + ((kb*16) ^ ((d & 7) << 4))) =
        *(const int4*)(wub + (size_t)(ch*64 + d)*DL_ + kb*8);
    }
    __syncthreads();
    f32x4 uacc[2]; uacc[0] = z4; uacc[1] = z4;
    #pragma unroll
    for (int ks = 0; ks < 4; ++ks) {
      short8_t bfrag = *(const short8_t*)(fcqrow + ((ks*64 + l4*16) ^ xsw));
      #pragma unroll
      for (int cf = 0; cf < 2; ++cf) {
        const int dd = wc*32 + cf*16 + l15;
        short8_t afrag = *(const short8_t*)(smb + WU_B + dd*256 +
                          ((ks*64 + l4*16) ^ ((dd & 7) << 4)));
        uacc[cf] = __builtin_amdgcn_mfma_f32_16x16x32_bf16(afrag, bfrag, uacc[cf], 0, 0, 0);
      }
    }
    #pragma unroll
    for (int cf = 0; cf < 2; ++cf) {
      const int d0 = ch*64 + wc*32 + cf*16 + l4*4;
      float4 bias = *(const float4*)(bc_up + d0);
      float4 fs4 = *(const float4*)(f_s + (size_t)b*D_ + d0);
      float4 fm4 = *(const float4*)(f_m + mbase + d0);
      float4 fc4 = *(const float4*)(f_c + obase + d0);
      float4 o;
      o.x = uacc[cf][0] + bias.x + fc4.x + fm4.x/(1.f + __expf(-fm4.x*fs4.x));
      o.y = uacc[cf][1] + bias.y + fc4.y + fm4.y/(1.f + __expf(-fm4.y*fs4.y));
      o.z = uacc[cf][2] + bias.z + fc4.z + fm4.z/(1.f + __expf(-fm4.z*fs4.z));
      o.w = uacc[cf][3] + bias.w + fc4.w + fm4.w/(1.f + __expf(-fm4.w*fs4.w));
      *(float4*)(out + obase + d0) = o;
    }
    __syncthreads();
  }
}

extern "C" void kernel_launch(void* const* d_in, const int* in_sizes, int n_in,
                              void* d_out, int out_size, void* d_ws, size_t ws_size,
                              hipStream_t stream) {
  (void)in_sizes; (void)n_in; (void)out_size; (void)ws_size;
  const float* f_c     = (const float*)d_in[0];
  const float* f_w     = (const float*)d_in[1];
  const float* f_s     = (const float*)d_in[2];
  const float* f_m     = (const float*)d_in[3];
  const float* Wc_down = (const float*)d_in[4];
  const float* bc_down = (const float*)d_in[5];
  const float* Ww      = (const float*)d_in[6];
  const float* bw      = (const float*)d_in[7];
  const float* Ws      = (const float*)d_in[8];
  const float* bs      = (const float*)d_in[9];
  const float* Wq      = (const float*)d_in[10];
  const float* bq      = (const float*)d_in[11];
  const float* Wk      = (const float*)d_in[12];
  const float* bk      = (const float*)d_in[13];
  const float* Wc_up   = (const float*)d_in[14];
  const float* bc_up   = (const float*)d_in[15];
  float* out = (float*)d_out;
  float* wsf = (float*)d_ws;
  unsigned short* wdb = (unsigned short*)(wsf + WS_WDB);
  unsigned short* wub = (unsigned short*)(wsf + WS_WUB);

  hipLaunchKernelGGL(k0_convert, dim3(128), dim3(256), 0, stream,
                     Wc_down, Wc_up, wdb, wub);
  hipLaunchKernelGGL(k1_small, dim3(B_*L_), dim3(128), 0, stream,
                     f_w, f_s, Ww, bw, Ws, bs, Wq, bq, Wk, bk, wsf);
  hipLaunchKernelGGL(k2_fused, dim3(M_/32), dim3(256), 0, stream,
                     f_c, wdb, wub, bc_down, bc_up, f_m, f_s, wsf, out);
}